// Round 8
// baseline (212.891 us; speedup 1.0000x reference)
//
#include <hip/hip_runtime.h>
#include <hip/hip_bf16.h>
#include <math.h>

// ---- problem constants ----
constexpr int BB    = 1024;
constexpr int NN    = 50;
constexpr int RR    = 1000;
constexpr int DD    = 128;
constexpr int NPOIS = 50000;
#define DEG2RADF  0.017453292519943295f
#define KHALF     0.008726646259971648f   // DEG2RAD/2
#define RSQRTD    0.08838834764831845f    // 1/sqrt(128)
#define DBIN_C0   4013.7373f
#define DBIN_C1   668.95621f
#define TBIN_SC   0.00625f                // 63/10080
#define PENAL     -1.0e30f                // additive mask sentinel

typedef __attribute__((ext_vector_type(8))) short bfrag8;
typedef __attribute__((ext_vector_type(4))) float f32x4;

// XOR-swizzled LDS tile addressing (shorts), row stride 128/64 shorts.
__device__ __forceinline__ int swz128(int row, int k) {
    return row * 128 + ((((k) >> 3) ^ (row & 7)) << 3) + (k & 7);
}
__device__ __forceinline__ int swz64(int row, int k) {
    return row * 64 + ((((k) >> 3) ^ (row & 7)) << 3) + (k & 7);
}

__device__ __forceinline__ unsigned short f2bf(float x) {
    union { __hip_bfloat16 h; unsigned short u; } cv;
    cv.h = __float2bfloat16(x);
    return cv.u;
}

__device__ __forceinline__ float cos_small(float x) {
    float x2 = x * x;
    return 1.0f - 0.5f * x2 + 0.041666667f * x2 * x2;
}

// conflict-free 64-entry table interp: table held per-lane in regs (eA=E[lane],
// eB=E[lane+1]); gather via LDS crossbar (ds_bpermute), no bank conflicts.
__device__ __forceinline__ float interp_bp(float eA, float eB, float pos) {
    int   k = (int)pos;
    float f = pos - (float)k;
    float lo = __int_as_float(__builtin_amdgcn_ds_bpermute(k << 2, __float_as_int(eA)));
    float hi = __int_as_float(__builtin_amdgcn_ds_bpermute(k << 2, __float_as_int(eB)));
    return fmaf(f, hi - lo, lo);
}

// ---- precompute (merged): Mt and G, both bf16 with 1/sqrt(D) folded ----
__global__ void prep_mg(const float* __restrict__ Wq, const float* __restrict__ Wk,
                        const float* __restrict__ Wv, const float* __restrict__ Re,
                        unsigned short* __restrict__ Mt, unsigned short* __restrict__ G) {
    int k = threadIdx.x;
    if (blockIdx.x < DD) {
        int c = blockIdx.x;
        float s0 = 0.f, s1 = 0.f, s2 = 0.f, s3 = 0.f;
        for (int d = 0; d < DD; d += 4) {
            s0 += Wq[(d + 0) * DD + k] * Wk[(d + 0) * DD + c];
            s1 += Wq[(d + 1) * DD + k] * Wk[(d + 1) * DD + c];
            s2 += Wq[(d + 2) * DD + k] * Wk[(d + 2) * DD + c];
            s3 += Wq[(d + 3) * DD + k] * Wk[(d + 3) * DD + c];
        }
        Mt[c * DD + k] = f2bf((s0 + s1 + s2 + s3) * RSQRTD);
    } else {
        int r = blockIdx.x - DD;
        float s0 = 0.f, s1 = 0.f, s2 = 0.f, s3 = 0.f;
        for (int d = 0; d < DD; d += 4) {
            s0 += Wv[(d + 0) * DD + k] * Re[r * DD + d + 0];
            s1 += Wv[(d + 1) * DD + k] * Re[r * DD + d + 1];
            s2 += Wv[(d + 2) * DD + k] * Re[r * DD + d + 2];
            s3 += Wv[(d + 3) * DD + k] * Re[r * DD + d + 3];
        }
        G[r * DD + k] = f2bf((s0 + s1 + s2 + s3) * RSQRTD);
    }
}

// ---- fused kernel: attention (per b) + all 16 match r-tiles for that b ----
// LDS: xs 16K (x, later Z) + u2 16K (Y / P) + Bs 2x16K (G dbuf) + tables
// = ~66.5 KB -> 2 blocks/CU; attn-MFMA of one block overlaps match-VALU of
// the other (m114 pipe co-scheduling).
__global__ __launch_bounds__(256) void stan_fused(
    const int* __restrict__ poi_idx, const int* __restrict__ hourw,
    const float* __restrict__ lat, const float* __restrict__ lon,
    const float* __restrict__ tmin,
    const float* __restrict__ poi_emb, const float* __restrict__ time_emb,
    const float* __restrict__ Et_g, const float* __restrict__ Ed_g,
    const float* __restrict__ Em_g, const float* __restrict__ cent,
    const unsigned short* __restrict__ Mtb, const unsigned short* __restrict__ G,
    float* __restrict__ out) {
    __shared__ short xs[64 * 128];             // x bf16 swizzled; later Z
    __shared__ union {
        short ys[64 * 128];                    // Y bf16 swizzled
        short ps[64 * 64];                     // P bf16 swizzled
    } u2;
    __shared__ short Bs[2][64 * 128];          // G tile double buffer
    __shared__ float4 bnfo[64];                // (lat*KHALF, lon*KHALF, cos, t*TBIN_SC)
    __shared__ float  jpen[64];                // 0 valid / -1e30 pad

    const int b = blockIdx.x, tid = threadIdx.x;
    const int wid = tid >> 6, lane = tid & 63;
    const int quad = lane >> 4, colr = lane & 15;

    // per-lane interp tables in registers (64 entries each)
    const int lp1 = lane < 63 ? lane + 1 : 63;
    const float etA = Et_g[lane], etB = Et_g[lp1];
    const float edA = Ed_g[lane], edB = Ed_g[lp1];
    const float emA = Em_g[lane], emB = Em_g[lp1];

    if (tid < 64) {
        if (tid < NN) {
            int p = poi_idx[b * NN + tid];
            float la = lat[b * NN + tid], lo = lon[b * NN + tid];
            bnfo[tid] = make_float4(la * KHALF, lo * KHALF,
                                    cos_small(la * DEG2RADF),
                                    tmin[b * NN + tid] * TBIN_SC);
            jpen[tid] = (p < 0) ? PENAL : 0.f;
        } else {
            bnfo[tid] = make_float4(0.f, 0.f, 1.f, 0.f);
            jpen[tid] = PENAL;
        }
    }
    __syncthreads();

    // ---- phase 1: gather x -> xs (bf16, swizzled u32 stores) ----
    for (int idx = tid; idx < 64 * 64; idx += 256) {
        int n = idx >> 6, c2 = idx & 63;
        float2 v = make_float2(0.f, 0.f);
        if (n < NN) {
            int p = poi_idx[b * NN + n];
            int pd = (p < 0);
            int ps_ = pd ? NPOIS : p;
            int hs  = pd ? 0 : hourw[b * NN + n];
            float2 pe = ((const float2*)(poi_emb  + (size_t)ps_ * DD))[c2];
            float2 te = ((const float2*)(time_emb + (size_t)hs  * DD))[c2];
            v = make_float2(pe.x + te.x, pe.y + te.y);
        }
        unsigned pack = (unsigned)f2bf(v.x) | ((unsigned)f2bf(v.y) << 16);
        ((unsigned*)xs)[n * 64 + (((c2 >> 2) ^ (n & 7)) << 2) + (c2 & 3)] = pack;
    }
    __syncthreads();

    // ---- phase 2: Y = x @ Mt^T (MFMA), Mt streamed from L1/L2 ----
    {
        f32x4 accY[2][4];
        #pragma unroll
        for (int ct = 0; ct < 2; ct++)
            #pragma unroll
            for (int mt = 0; mt < 4; mt++) accY[ct][mt] = (f32x4){0.f, 0.f, 0.f, 0.f};
        #pragma unroll
        for (int ks = 0; ks < 4; ks++) {
            const int k0 = ks * 32 + quad * 8;
            bfrag8 av[4], bv[2];
            #pragma unroll
            for (int mt = 0; mt < 4; mt++)
                av[mt] = *(const bfrag8*)(&xs[swz128(mt * 16 + colr, k0)]);
            #pragma unroll
            for (int ct = 0; ct < 2; ct++) {
                int c = wid * 32 + ct * 16 + colr;
                bv[ct] = *(const bfrag8*)(Mtb + (size_t)c * DD + k0);
            }
            #pragma unroll
            for (int ct = 0; ct < 2; ct++)
                #pragma unroll
                for (int mt = 0; mt < 4; mt++)
                    accY[ct][mt] = __builtin_amdgcn_mfma_f32_16x16x32_bf16(
                        av[mt], bv[ct], accY[ct][mt], 0, 0, 0);
        }
        #pragma unroll
        for (int ct = 0; ct < 2; ct++)
            #pragma unroll
            for (int mt = 0; mt < 4; mt++)
                #pragma unroll
                for (int reg = 0; reg < 4; reg++) {
                    int m = mt * 16 + quad * 4 + reg;
                    int c = wid * 32 + ct * 16 + colr;
                    u2.ys[swz128(m, c)] = (short)f2bf(accY[ct][mt][reg]);
                }
    }
    __syncthreads();

    // ---- phase 3: S^T = x @ Y^T (MFMA). C: row=j, col=i=wid*16+colr ----
    const int i = wid * 16 + colr;
    f32x4 accS[4];
    #pragma unroll
    for (int mt = 0; mt < 4; mt++) accS[mt] = (f32x4){0.f, 0.f, 0.f, 0.f};
    #pragma unroll
    for (int ks = 0; ks < 4; ks++) {
        const int k0 = ks * 32 + quad * 8;
        bfrag8 bv = *(const bfrag8*)(&u2.ys[swz128(i, k0)]);
        #pragma unroll
        for (int mt = 0; mt < 4; mt++) {
            bfrag8 av = *(const bfrag8*)(&xs[swz128(mt * 16 + colr, k0)]);
            accS[mt] = __builtin_amdgcn_mfma_f32_16x16x32_bf16(
                av, bv, accS[mt], 0, 0, 0);
        }
    }
    __syncthreads();   // ys reads done; ps may overwrite union

    // ---- attn bias + in-register softmax over j (column i) ----
    {
        const float4 bi = bnfo[i];
        float sv[16];
        #pragma unroll
        for (int mt = 0; mt < 4; mt++) {
            #pragma unroll
            for (int reg = 0; reg < 4; reg++) {
                int j = mt * 16 + quad * 4 + reg;
                float4 bj = bnfo[j];
                float bt = interp_bp(etA, etB, fabsf(bi.w - bj.w));
                float du = bi.x - bj.x, dv = bi.y - bj.y;
                float a = fmaf((bi.z * bj.z) * dv, dv, du * du);
                float x = __builtin_amdgcn_sqrtf(a);
                float bd = interp_bp(edA, edB, x * fmaf(a, DBIN_C1, DBIN_C0));
                sv[mt * 4 + reg] = (accS[mt][reg] + bt) + (bd + jpen[j]);
            }
        }
        float mx = sv[0];
        #pragma unroll
        for (int t = 1; t < 16; t++) mx = fmaxf(mx, sv[t]);
        mx = fmaxf(mx, __shfl_xor(mx, 16, 64));
        mx = fmaxf(mx, __shfl_xor(mx, 32, 64));
        float l = 0.f;
        #pragma unroll
        for (int t = 0; t < 16; t++) {
            float p = __expf(sv[t] - mx);
            sv[t] = p;
            l += p;
        }
        l += __shfl_xor(l, 16, 64);
        l += __shfl_xor(l, 32, 64);
        float rl = __builtin_amdgcn_rcpf(l);   // l >= 1 (max attained)
        #pragma unroll
        for (int mt = 0; mt < 4; mt++)
            #pragma unroll
            for (int rp = 0; rp < 2; rp++) {
                int j0 = mt * 16 + quad * 4 + rp * 2;
                unsigned lo = f2bf(sv[mt * 4 + rp * 2]     * rl);
                unsigned hi = f2bf(sv[mt * 4 + rp * 2 + 1] * rl);
                ((unsigned*)u2.ps)[i * 32 + (((j0 >> 3) ^ (i & 7)) << 2) + ((j0 & 7) >> 1)]
                    = lo | (hi << 16);
            }
    }
    __syncthreads();

    // ---- phase 4: Z = P @ x (K=64 over j); B-frags gathered from xs columns ----
    f32x4 accZ[2][4];
    #pragma unroll
    for (int nt = 0; nt < 2; nt++)
        #pragma unroll
        for (int mt = 0; mt < 4; mt++) accZ[nt][mt] = (f32x4){0.f, 0.f, 0.f, 0.f};
    {
        union BF { unsigned u[4]; bfrag8 v; };
        #pragma unroll
        for (int ks = 0; ks < 2; ks++) {
            const int k0 = ks * 32 + quad * 8;
            bfrag8 av[4];
            #pragma unroll
            for (int mt = 0; mt < 4; mt++)
                av[mt] = *(const bfrag8*)(&u2.ps[swz64(mt * 16 + colr, k0)]);
            BF bvx[2];
            #pragma unroll
            for (int nt = 0; nt < 2; nt++) {
                int d = wid * 32 + nt * 16 + colr;
                #pragma unroll
                for (int t2 = 0; t2 < 4; t2++) {
                    unsigned lo = (unsigned short)xs[swz128(k0 + 2 * t2,     d)];
                    unsigned hi = (unsigned short)xs[swz128(k0 + 2 * t2 + 1, d)];
                    bvx[nt].u[t2] = lo | (hi << 16);
                }
            }
            #pragma unroll
            for (int nt = 0; nt < 2; nt++)
                #pragma unroll
                for (int mt = 0; mt < 4; mt++)
                    accZ[nt][mt] = __builtin_amdgcn_mfma_f32_16x16x32_bf16(
                        av[mt], bvx[nt].v, accZ[nt][mt], 0, 0, 0);
        }
    }
    __syncthreads();   // all xs reads done; xs becomes the Z tile

    // ---- write Z -> xs (swizzled, bf16) + prefetch G tile 0 ----
    uint4 g4;
    const int grow = tid >> 2, gcol = (tid & 3) * 32;   // staging coords
    {
        int gr0 = grow; if (gr0 > RR - 1) gr0 = RR - 1;
        g4 = *(const uint4*)(G + (size_t)gr0 * DD + gcol);
        #pragma unroll
        for (int mt = 0; mt < 4; mt++)
            #pragma unroll
            for (int reg = 0; reg < 4; reg++) {
                int zi = mt * 16 + quad * 4 + reg;
                #pragma unroll
                for (int nt = 0; nt < 2; nt++) {
                    int d = wid * 32 + nt * 16 + colr;
                    xs[swz128(zi, d)] = (short)f2bf(accZ[nt][mt][reg]);
                }
            }
    }
    // hoist tile-invariant per-n data into registers (n pattern fixed per lane)
    float bnx[16], bny[16], bnz[16], pen[16];
    #pragma unroll
    for (int mt = 0; mt < 4; mt++)
        #pragma unroll
        for (int reg = 0; reg < 4; reg++) {
            int n = mt * 16 + quad * 4 + reg;
            float4 bn = bnfo[n];
            bnx[mt * 4 + reg] = bn.x; bny[mt * 4 + reg] = bn.y;
            bnz[mt * 4 + reg] = bn.z; pen[mt * 4 + reg] = jpen[n];
        }
    {   // store G tile 0 into Bs[0]
        const int jb = (tid & 3) * 4, rx = grow & 7;
        ((uint4*)Bs[0])[grow * 16 + (jb ^ rx)] = g4;
        // note: only first of 4 blocks stored by this thread? No: one uint4
        // per thread per tile (16 KB / 256 thr = 64 B? 16384/256 = 64 B = 4 uint4)
    }
    // correction: each thread stages 4 uint4 per tile (64 B). Redo properly:
    // (the single-uint4 path above covers only 1/4 of the tile; load the rest)
    uint4 g4b, g4c, g4d;
    {
        int gr0 = grow; if (gr0 > RR - 1) gr0 = RR - 1;
        const uint4* src = (const uint4*)(G + (size_t)gr0 * DD + gcol);
        g4b = src[1]; g4c = src[2]; g4d = src[3];
        const int jb = (tid & 3) * 4, rx = grow & 7;
        uint4* dst = (uint4*)Bs[0];
        dst[grow * 16 + ((jb + 1) ^ rx)] = g4b;
        dst[grow * 16 + ((jb + 2) ^ rx)] = g4c;
        dst[grow * 16 + ((jb + 3) ^ rx)] = g4d;
    }
    __syncthreads();   // Z visible, Bs[0] ready

    // ---- match loop over 16 r-tiles, double-buffered G staging ----
    const int rL = wid * 16 + colr;
    for (int rt = 0; rt < 16; rt++) {
        const int cur = rt & 1;
        uint4 n0, n1, n2, n3;
        if (rt < 15) {   // issue next-tile loads (latency hidden by compute)
            int gr = (rt + 1) * 64 + grow; if (gr > RR - 1) gr = RR - 1;
            const uint4* src = (const uint4*)(G + (size_t)gr * DD + gcol);
            n0 = src[0]; n1 = src[1]; n2 = src[2]; n3 = src[3];
        }

        f32x4 acc[4];
        #pragma unroll
        for (int mt = 0; mt < 4; mt++) acc[mt] = (f32x4){0.f, 0.f, 0.f, 0.f};
        #pragma unroll
        for (int ks = 0; ks < 4; ks++) {
            const int k0 = ks * 32 + quad * 8;
            bfrag8 bf = *(const bfrag8*)(&Bs[cur][swz128(rL, k0)]);
            #pragma unroll
            for (int mt = 0; mt < 4; mt++) {
                bfrag8 af = *(const bfrag8*)(&xs[swz128(mt * 16 + colr, k0)]);
                acc[mt] = __builtin_amdgcn_mfma_f32_16x16x32_bf16(af, bf, acc[mt], 0, 0, 0);
            }
        }

        const int r = rt * 64 + rL;
        int rc = r > RR - 1 ? RR - 1 : r;
        float2 cc = ((const float2*)cent)[rc];
        const float rvx = cc.x * KHALF, rvy = cc.y * KHALF;
        const float rvz = cos_small(cc.x * DEG2RADF);

        float s[16];
        #pragma unroll
        for (int t = 0; t < 16; t++) {
            float du = bnx[t] - rvx, dv = bny[t] - rvy;
            float a = fmaf((bnz[t] * rvz) * dv, dv, du * du);
            float x = __builtin_amdgcn_sqrtf(a);
            float bias = interp_bp(emA, emB, x * fmaf(a, DBIN_C1, DBIN_C0));
            s[t] = (acc[t >> 2][t & 3] + bias) + pen[t];
        }
        float m = s[0];
        #pragma unroll
        for (int t = 1; t < 16; t++) m = fmaxf(m, s[t]);
        m = fmaxf(m, __shfl_xor(m, 16, 64));
        m = fmaxf(m, __shfl_xor(m, 32, 64));
        float l = 0.f, a = 0.f;
        #pragma unroll
        for (int t = 0; t < 16; t++) {
            float p = __expf(s[t] - m);
            l += p;
            a = fmaf(p, s[t], a);
        }
        l += __shfl_xor(l, 16, 64); a += __shfl_xor(a, 16, 64);
        l += __shfl_xor(l, 32, 64); a += __shfl_xor(a, 32, 64);
        if (quad == 0 && r < RR)
            out[(size_t)b * RR + r] = a * __builtin_amdgcn_rcpf(l);

        if (rt < 15) {   // store next tile into the other buffer
            const int jb = (tid & 3) * 4, rx = grow & 7;
            uint4* dst = (uint4*)Bs[cur ^ 1];
            dst[grow * 16 + ((jb + 0) ^ rx)] = n0;
            dst[grow * 16 + ((jb + 1) ^ rx)] = n1;
            dst[grow * 16 + ((jb + 2) ^ rx)] = n2;
            dst[grow * 16 + ((jb + 3) ^ rx)] = n3;
        }
        __syncthreads();
    }
}

extern "C" void kernel_launch(void* const* d_in, const int* in_sizes, int n_in,
                              void* d_out, int out_size, void* d_ws, size_t ws_size,
                              hipStream_t stream) {
    const int*   poi_idx  = (const int*)d_in[0];
    const int*   hourw    = (const int*)d_in[1];
    const float* lat      = (const float*)d_in[2];
    const float* lon      = (const float*)d_in[3];
    const float* tmin     = (const float*)d_in[4];
    const float* cent     = (const float*)d_in[5];
    const float* poi_emb  = (const float*)d_in[6];
    const float* time_emb = (const float*)d_in[7];
    const float* E_t      = (const float*)d_in[8];
    const float* E_d      = (const float*)d_in[9];
    const float* E_dm     = (const float*)d_in[10];
    const float* Remb     = (const float*)d_in[11];
    const float* Wq       = (const float*)d_in[12];
    const float* Wk       = (const float*)d_in[13];
    const float* Wv       = (const float*)d_in[14];
    float* out            = (float*)d_out;

    unsigned short* Mtb = (unsigned short*)d_ws;            // 128*128 bf16 (32 KB)
    unsigned short* Gb  = Mtb + DD * DD;                    // 1000*128 bf16 (256 KB)

    prep_mg<<<dim3(DD + RR), DD, 0, stream>>>(Wq, Wk, Wv, Remb, Mtb, Gb);
    stan_fused<<<dim3(BB), 256, 0, stream>>>(poi_idx, hourw, lat, lon, tmin,
                                             poi_emb, time_emb, E_t, E_d, E_dm,
                                             cent, Mtb, Gb, out);
}